// Round 1
// baseline (54.875 us; speedup 1.0000x reference)
//
#include <hip/hip_runtime.h>

#define NCH 8

__device__ __forceinline__ int lower_bound_i32(const int* __restrict__ a, int n, int key) {
    int lo = 0, hi = n;
    while (lo < hi) {
        int mid = (lo + hi) >> 1;
        if (a[mid] < key) lo = mid + 1; else hi = mid;
    }
    return lo;
}

// Kernel S: per-frustum start offsets via parallel binary search over sorted i_frustum.
__global__ __launch_bounds__(256) void k_starts(const int* __restrict__ i_frustum, int n, int F,
                                                int* __restrict__ starts) {
    int t = blockIdx.x * blockDim.x + threadIdx.x;
    if (t <= F) starts[t] = lower_bound_i32(i_frustum, n, t);
}

// Kernel A: one block per frustum; single pass -> sum, sumsq, max -> mean, std, frustum_max.
__global__ __launch_bounds__(256) void k_stats(
    const float* __restrict__ pc, const float* __restrict__ counts,
    const int* __restrict__ starts,
    float* __restrict__ out_mean, float* __restrict__ out_std, float* __restrict__ out_max)
{
    int f = blockIdx.x;
    int s = starts[f];
    int e = starts[f + 1];
    int tid = threadIdx.x;

    float sum = 0.f, sq = 0.f, mx = 0.f;  // mx init 0 == scatter-max onto zeros (include_self)
    // Flattened element loop: thread tid has fixed channel (tid & 7) since stride 256 % 8 == 0.
    for (int idx = s * NCH + tid; idx < e * NCH; idx += 256) {
        float v = pc[idx];
        sum += v;
        sq  += v * v;
        mx   = fmaxf(mx, v);
    }
    // Wave-level reduce: combine lanes with the same channel (lane bits 3..5).
    #pragma unroll
    for (int m = 8; m <= 32; m <<= 1) {
        sum += __shfl_xor(sum, m, 64);
        sq  += __shfl_xor(sq,  m, 64);
        mx   = fmaxf(mx, __shfl_xor(mx, m, 64));
    }
    __shared__ float red[3][4][NCH];
    int w = tid >> 6, lane = tid & 63;
    if (lane < NCH) {
        red[0][w][lane] = sum;
        red[1][w][lane] = sq;
        red[2][w][lane] = mx;
    }
    __syncthreads();
    if (tid < NCH) {
        float S = 0.f, Q = 0.f, M = 0.f;
        #pragma unroll
        for (int ww = 0; ww < 4; ++ww) {
            S += red[0][ww][tid];
            Q += red[1][ww][tid];
            M  = fmaxf(M, red[2][ww][tid]);
        }
        float cnt  = counts[f];
        float invc = 1.0f / fmaxf(cnt, 1.0f);
        float mean = S * invc;                      // empty frustum: S==0 -> 0 (matches where())
        float var  = fmaxf(Q * invc - mean * mean, 0.0f);
        float sd   = sqrtf(var);                    // var==0 -> 0, matches where(var>0, sqrt, var)
        out_mean[f * NCH + tid] = mean;
        out_std [f * NCH + tid] = sd;
        out_max [f * NCH + tid] = M;
    }
}

// Kernel B: per-point normalize with faithful double-gather f = i_frustum[i_inv[i]].
__global__ __launch_bounds__(256) void k_norm(
    const float* __restrict__ pc, const int* __restrict__ i_frustum,
    const int* __restrict__ i_inv,
    const float* __restrict__ meanb, const float* __restrict__ stdb,
    float* __restrict__ out, int n)
{
    int i = blockIdx.x * blockDim.x + threadIdx.x;
    if (i >= n) return;
    int j = i_inv[i];
    int f = i_frustum[j];

    const float4* pm = reinterpret_cast<const float4*>(meanb + (size_t)f * NCH);
    const float4* ps = reinterpret_cast<const float4*>(stdb  + (size_t)f * NCH);
    const float4* pp = reinterpret_cast<const float4*>(pc    + (size_t)i * NCH);
    float4*       po = reinterpret_cast<float4*>(out + (size_t)i * NCH);

    float4 m0 = pm[0], m1 = pm[1];
    float4 s0 = ps[0], s1 = ps[1];
    float4 p0 = pp[0], p1 = pp[1];
    float4 o0, o1;
    o0.x = (p0.x - m0.x) / (s0.x > 0.f ? s0.x : 1.f);
    o0.y = (p0.y - m0.y) / (s0.y > 0.f ? s0.y : 1.f);
    o0.z = (p0.z - m0.z) / (s0.z > 0.f ? s0.z : 1.f);
    o0.w = (p0.w - m0.w) / (s0.w > 0.f ? s0.w : 1.f);
    o1.x = (p1.x - m1.x) / (s1.x > 0.f ? s1.x : 1.f);
    o1.y = (p1.y - m1.y) / (s1.y > 0.f ? s1.y : 1.f);
    o1.z = (p1.z - m1.z) / (s1.z > 0.f ? s1.z : 1.f);
    o1.w = (p1.w - m1.w) / (s1.w > 0.f ? s1.w : 1.f);
    po[0] = o0;
    po[1] = o1;
}

extern "C" void kernel_launch(void* const* d_in, const int* in_sizes, int n_in,
                              void* d_out, int out_size, void* d_ws, size_t ws_size,
                              hipStream_t stream) {
    const float* pc        = (const float*)d_in[0];
    const int*   i_frustum = (const int*)d_in[1];
    const int*   i_inv     = (const int*)d_in[2];
    const float* counts    = (const float*)d_in[3];

    int n = in_sizes[0] / NCH;   // 2,000,000 points
    int F = in_sizes[3];         // 14,400 frustums

    float* out_mean = (float*)d_out;
    float* out_std  = out_mean + (size_t)F * NCH;
    float* out_max  = out_std  + (size_t)F * NCH;
    float* out_pcn  = out_max  + (size_t)F * NCH;

    int* starts = (int*)d_ws;    // F+1 ints

    k_starts<<<(F + 1 + 255) / 256, 256, 0, stream>>>(i_frustum, n, F, starts);
    k_stats<<<F, 256, 0, stream>>>(pc, counts, starts, out_mean, out_std, out_max);
    k_norm<<<(n + 255) / 256, 256, 0, stream>>>(pc, i_frustum, i_inv, out_mean, out_std, out_pcn, n);
}